// Round 9
// baseline (97.325 us; speedup 1.0000x reference)
//
#include <hip/hip_runtime.h>
#include <math.h>

#define IN_C 64
#define OUT_C 16

typedef float f4 __attribute__((ext_vector_type(4)));
typedef float f2 __attribute__((ext_vector_type(2)));

// ws layout (floats):
//   [0..63]   cst: [0]=P [1]=Q [2..17]=r_j=b1/w1 [18..33]=sp_j=0.5*w2*|w1|
//   [64..]    T[N][32] = { h[16], exn[16] }   (128 B/row, line-aligned)

// ---------------------------------------------------------------------------
// Kernel 1: h = x @ W_lin + b_lin, exn[k] = exp(score(h[k])), packed into T.
// Folded MLP: score(c) = P*c + Q + sum_j sp_j * |c + r_j|  (no max-shift
// softmax downstream; scores are O(1) so exp is safe in fp32).
// ---------------------------------------------------------------------------
__global__ __launch_bounds__(256) void node_pack_kernel(
    const float* __restrict__ x, const float* __restrict__ W_lin,
    const float* __restrict__ b_lin,
    const float* __restrict__ w1, const float* __restrict__ b1,
    const float* __restrict__ w2, const float* __restrict__ b2,
    float* __restrict__ cst, float* __restrict__ T, int N)
{
    __shared__ float sW[IN_C * OUT_C];   // 4 KB
    __shared__ float sb[OUT_C];
    for (int i = threadIdx.x; i < IN_C * OUT_C; i += blockDim.x) sW[i] = W_lin[i];
    if (threadIdx.x < OUT_C) sb[threadIdx.x] = b_lin[threadIdx.x];
    __syncthreads();

    // folded constants (uniform; cheap per thread)
    float rj[16], spj[16];
    float P = 0.f, Q = b2[0];
    #pragma unroll
    for (int j = 0; j < 16; j++) {
        float w = w1[j], b = b1[j], s = 0.5f * w2[j];
        rj[j]  = b / w;
        spj[j] = s * fabsf(w);
        P = fmaf(w, s, P);
        Q = fmaf(b, s, Q);
    }
    if (blockIdx.x == 0 && threadIdx.x == 0) {
        cst[0] = P; cst[1] = Q;
        #pragma unroll
        for (int j = 0; j < 16; j++) {
            cst[2 + j]  = rj[j];
            cst[18 + j] = spj[j];
        }
    }

    int n = blockIdx.x * blockDim.x + threadIdx.x;
    if (n >= N) return;

    float acc[OUT_C];
    #pragma unroll
    for (int j = 0; j < OUT_C; j++) acc[j] = sb[j];

    const f4* xr = (const f4*)(x + (size_t)n * IN_C);
    #pragma unroll
    for (int k4 = 0; k4 < IN_C / 4; k4++) {
        f4 xv = __builtin_nontemporal_load(xr + k4);
        #pragma unroll
        for (int kk = 0; kk < 4; kk++) {
            const float xs = xv[kk];
            const f4* wrow = (const f4*)(sW + (k4 * 4 + kk) * OUT_C);
            #pragma unroll
            for (int jq = 0; jq < 4; jq++) {
                f4 wv = wrow[jq];
                acc[jq * 4 + 0] = fmaf(xs, wv[0], acc[jq * 4 + 0]);
                acc[jq * 4 + 1] = fmaf(xs, wv[1], acc[jq * 4 + 1]);
                acc[jq * 4 + 2] = fmaf(xs, wv[2], acc[jq * 4 + 2]);
                acc[jq * 4 + 3] = fmaf(xs, wv[3], acc[jq * 4 + 3]);
            }
        }
    }

    // per-node score exps
    float ex[OUT_C];
    #pragma unroll
    for (int k = 0; k < OUT_C; k++) {
        const float cv = acc[k];
        float a = fmaf(P, cv, Q);
        #pragma unroll
        for (int j = 0; j < 16; j++)
            a = fmaf(fabsf(cv + rj[j]), spj[j], a);
        ex[k] = __expf(a);
    }

    // packed 128 B row: [h(16) | exn(16)]  — PLAIN stores (want T cached)
    f4* Tp = (f4*)(T + (size_t)n * 32);
    #pragma unroll
    for (int jq = 0; jq < 4; jq++) {
        f4 o, p;
        o[0] = acc[jq*4+0]; o[1] = acc[jq*4+1]; o[2] = acc[jq*4+2]; o[3] = acc[jq*4+3];
        p[0] = ex[jq*4+0];  p[1] = ex[jq*4+1];  p[2] = ex[jq*4+2];  p[3] = ex[jq*4+3];
        Tp[jq]     = o;
        Tp[4 + jq] = p;
    }
}

// ---------------------------------------------------------------------------
// Kernel 2: EIGHT lanes per edge, ONE random (cached) line per edge.
// Streaming traffic (edge_attr, col in; out store) is NON-TEMPORAL so it
// cannot evict the T gather table from L2/L3. The out store is safe for NT
// because each wave's store instr is 1 KB fully-contiguous (8 whole lines) —
// unlike R4's partial-line scatter which amplified 3x.
// ---------------------------------------------------------------------------
__global__ __launch_bounds__(256) void edge_attn8_kernel(
    const float* __restrict__ edge_attr, const int* __restrict__ col,
    const float* __restrict__ W_edge, const float* __restrict__ b_edge,
    const float* __restrict__ cst, const float* __restrict__ T,
    float* __restrict__ out, int E)
{
    __shared__ float sWe[8 * OUT_C];   // [d][j] row-major, 512 B
    __shared__ float sbe[OUT_C];
    if (threadIdx.x < 32)
        ((f4*)sWe)[threadIdx.x] = ((const f4*)W_edge)[threadIdx.x];
    if (threadIdx.x < 4)
        ((f4*)sbe)[threadIdx.x] = ((const f4*)b_edge)[threadIdx.x];
    __syncthreads();

    const int tid = blockIdx.x * 256 + threadIdx.x;
    int e = tid >> 3;
    const bool valid = e < E;
    if (!valid) e = E - 1;
    const int lane = threadIdx.x & 63;
    const int sub  = lane & 7;
    const int base = lane & 56;

    // ---- memory: 1 random cached line + NT streams --------------------
    const int c = __builtin_nontemporal_load(col + e);
    f4 t = ((const f4*)(T + (size_t)c * 32))[sub];          // cached gather

    const f4* ep = (const f4*)(edge_attr + (size_t)e * 8);
    f4 eaA = __builtin_nontemporal_load(ep);
    f4 eaB = __builtin_nontemporal_load(ep + 1);
    float ear[8] = {eaA[0], eaA[1], eaA[2], eaA[3],
                    eaB[0], eaB[1], eaB[2], eaB[3]};

    // ---- ea columns 2sub, 2sub+1 --------------------------------------
    f2 bp = ((const f2*)sbe)[sub];
    float eax = bp[0], eay = bp[1];
    #pragma unroll
    for (int d = 0; d < 8; d++) {
        f2 w = ((const f2*)sWe)[d * 8 + sub];
        eax = fmaf(ear[d], w[0], eax);
        eay = fmaf(ear[d], w[1], eay);
    }

    // ---- 2 scores -> exps (uniform consts are SGPR s_loads) -----------
    const float P = cst[0], Q = cst[1];
    float a0 = fmaf(P, eax, Q);
    float a1 = fmaf(P, eay, Q);
    #pragma unroll
    for (int j = 0; j < 16; j++) {
        const float r  = cst[2 + j];
        const float sp = cst[18 + j];
        a0 = fmaf(fabsf(eax + r), sp, a0);
        a1 = fmaf(fabsf(eay + r), sp, a1);
    }
    const float ex0 = __expf(a0);
    const float ex1 = __expf(a1);

    // ---- denominator: node exps live in lanes 4..7's quads ------------
    const float tq = (t[0] + t[1]) + (t[2] + t[3]);
    float ps = ex0 + ex1 + ((sub >= 4) ? tq : 0.f);
    ps += __shfl_xor(ps, 1, 64);
    ps += __shfl_xor(ps, 2, 64);
    ps += __shfl_xor(ps, 4, 64);
    const float inv = __builtin_amdgcn_rcpf(ps);

    // ---- redistribute: nv pair, exn quad, edge-exp quad ---------------
    const int srcNV = base | (sub >> 1);             // lane with nv[4*(sub>>1)..]
    float n0 = __shfl(t[0], srcNV, 64), n1 = __shfl(t[1], srcNV, 64);
    float n2 = __shfl(t[2], srcNV, 64), n3 = __shfl(t[3], srcNV, 64);
    const bool hi = (sub & 1);
    const float nvA = hi ? n2 : n0;                  // nv[2sub]
    const float nvB = hi ? n3 : n1;                  // nv[2sub+1]

    const int srcEX = base | (sub & 3) | 4;          // lane with exn[4(sub&3)..]
    float q0 = __shfl(t[0], srcEX, 64), q1 = __shfl(t[1], srcEX, 64);
    float q2 = __shfl(t[2], srcEX, 64), q3 = __shfl(t[3], srcEX, 64);

    const int s2 = (sub & 3) * 2;                    // edge-exp sources
    const int srcE0 = base | s2, srcE1 = base | (s2 + 1);
    float g0 = __shfl(ex0, srcE0, 64), g1 = __shfl(ex1, srcE0, 64);
    float g2 = __shfl(ex0, srcE1, 64), g3 = __shfl(ex1, srcE1, 64);

    const bool lo = (sub < 4);
    const float m0 = lo ? q0 : g0, m1 = lo ? q1 : g1;
    const float m2 = lo ? q2 : g2, m3 = lo ? q3 : g3;

    // ---- out[e][4sub + 0..3] = nv[(4sub+t)>>1] * attn ------------------
    if (valid) {
        const float sA = nvA * inv, sB = nvB * inv;
        f4 o;
        o[0] = sA * m0; o[1] = sA * m1;
        o[2] = sB * m2; o[3] = sB * m3;
        __builtin_nontemporal_store(o, ((f4*)(out + (size_t)e * 32)) + sub);
    }
}

// ---------------------------------------------------------------------------
extern "C" void kernel_launch(void* const* d_in, const int* in_sizes, int n_in,
                              void* d_out, int out_size, void* d_ws, size_t ws_size,
                              hipStream_t stream) {
    const float* x         = (const float*)d_in[0];
    const float* edge_attr = (const float*)d_in[1];
    const int*   col       = (const int*)d_in[2];
    const float* W_lin     = (const float*)d_in[3];
    const float* b_lin     = (const float*)d_in[4];
    const float* W_edge    = (const float*)d_in[5];
    const float* b_edge    = (const float*)d_in[6];
    const float* w1        = (const float*)d_in[7];
    const float* b1        = (const float*)d_in[8];
    const float* w2        = (const float*)d_in[9];
    const float* b2        = (const float*)d_in[10];
    float* out = (float*)d_out;

    const int N = in_sizes[0] / IN_C;     // 100000
    const int E = in_sizes[1] / 8;        // 1000000

    float* cst = (float*)d_ws;            // 64 floats (keeps T 256B-aligned)
    float* T   = cst + 64;                // N*32 floats = 12.8 MB

    dim3 blk(256);
    dim3 grid1((N + 255) / 256);
    node_pack_kernel<<<grid1, blk, 0, stream>>>(x, W_lin, b_lin,
                                                w1, b1, w2, b2, cst, T, N);

    long long total = (long long)E * 8;   // 8 threads per edge
    dim3 grid2((unsigned)((total + 255) / 256));
    edge_attn8_kernel<<<grid2, blk, 0, stream>>>(edge_attr, col, W_edge, b_edge,
                                                 cst, T, out, E);
}

// Round 10
// 77.588 us; speedup vs baseline: 1.2544x; 1.2544x over previous
//
#include <hip/hip_runtime.h>
#include <math.h>

#define IN_C 64
#define OUT_C 16

typedef float f4 __attribute__((ext_vector_type(4)));
typedef float f2 __attribute__((ext_vector_type(2)));
typedef unsigned int u32;
typedef unsigned long long u64;
typedef u32 u4 __attribute__((ext_vector_type(4)));

// ws layout:
//   [0..63]   cst (f32): [0]=P [1]=Q [2..17]=r_j=b1/w1 [18..33]=sp_j=0.5*w2*|w1|
//   [64..]    T[N] rows of 64 B: [ h[16] bf16 | exn[16] bf16 ]  (6.4 MB)

__device__ __forceinline__ u32 bf16r(float f) {      // round-to-nearest-even
    u32 b = __float_as_uint(f);
    b += 0x7fffu + ((b >> 16) & 1u);
    return b >> 16;
}

// ---------------------------------------------------------------------------
// Kernel 1: h = x @ W_lin + b_lin; exn[k] = exp(score(h[k])); pack bf16 into T.
// Folded MLP: score(c) = P*c + Q + sum_j sp_j * |c + r_j|   (no max-shift
// softmax downstream; scores are O(1) so fp32 exp is safe).
// ---------------------------------------------------------------------------
__global__ __launch_bounds__(256) void node_pack_kernel(
    const float* __restrict__ x, const float* __restrict__ W_lin,
    const float* __restrict__ b_lin,
    const float* __restrict__ w1, const float* __restrict__ b1,
    const float* __restrict__ w2, const float* __restrict__ b2,
    float* __restrict__ cst, u32* __restrict__ T, int N)
{
    __shared__ float sW[IN_C * OUT_C];   // 4 KB
    __shared__ float sb[OUT_C];
    for (int i = threadIdx.x; i < IN_C * OUT_C; i += blockDim.x) sW[i] = W_lin[i];
    if (threadIdx.x < OUT_C) sb[threadIdx.x] = b_lin[threadIdx.x];
    __syncthreads();

    // folded constants (uniform, cheap per thread)
    float rj[16], spj[16];
    float P = 0.f, Q = b2[0];
    #pragma unroll
    for (int j = 0; j < 16; j++) {
        float w = w1[j], b = b1[j], s = 0.5f * w2[j];
        rj[j]  = b / w;
        spj[j] = s * fabsf(w);
        P = fmaf(w, s, P);
        Q = fmaf(b, s, Q);
    }
    if (blockIdx.x == 0 && threadIdx.x == 0) {
        cst[0] = P; cst[1] = Q;
        #pragma unroll
        for (int j = 0; j < 16; j++) {
            cst[2 + j]  = rj[j];
            cst[18 + j] = spj[j];
        }
    }

    int n = blockIdx.x * blockDim.x + threadIdx.x;
    if (n >= N) return;

    float acc[OUT_C];
    #pragma unroll
    for (int j = 0; j < OUT_C; j++) acc[j] = sb[j];

    const f4* xr = (const f4*)(x + (size_t)n * IN_C);
    #pragma unroll
    for (int k4 = 0; k4 < IN_C / 4; k4++) {
        f4 xv = __builtin_nontemporal_load(xr + k4);
        #pragma unroll
        for (int kk = 0; kk < 4; kk++) {
            const float xs = xv[kk];
            const f4* wrow = (const f4*)(sW + (k4 * 4 + kk) * OUT_C);
            #pragma unroll
            for (int jq = 0; jq < 4; jq++) {
                f4 wv = wrow[jq];
                acc[jq * 4 + 0] = fmaf(xs, wv[0], acc[jq * 4 + 0]);
                acc[jq * 4 + 1] = fmaf(xs, wv[1], acc[jq * 4 + 1]);
                acc[jq * 4 + 2] = fmaf(xs, wv[2], acc[jq * 4 + 2]);
                acc[jq * 4 + 3] = fmaf(xs, wv[3], acc[jq * 4 + 3]);
            }
        }
    }

    // per-node score exps
    float ex[OUT_C];
    #pragma unroll
    for (int k = 0; k < OUT_C; k++) {
        const float cv = acc[k];
        float a = fmaf(P, cv, Q);
        #pragma unroll
        for (int j = 0; j < 16; j++)
            a = fmaf(fabsf(cv + rj[j]), spj[j], a);
        ex[k] = __expf(a);
    }

    // pack 64 B row: 8 u32 of h-pairs, 8 u32 of exn-pairs (plain stores: cached)
    u4 w0, w1v_, w2v_, w3v_;
    #pragma unroll
    for (int q = 0; q < 4; q++) {
        w0[q]   = bf16r(acc[2*q])     | (bf16r(acc[2*q+1])     << 16);
        w1v_[q] = bf16r(acc[8+2*q])   | (bf16r(acc[8+2*q+1])   << 16);
        w2v_[q] = bf16r(ex[2*q])      | (bf16r(ex[2*q+1])      << 16);
        w3v_[q] = bf16r(ex[8+2*q])    | (bf16r(ex[8+2*q+1])    << 16);
    }
    u4* Tp = (u4*)(T + (size_t)n * 16);
    Tp[0] = w0; Tp[1] = w1v_; Tp[2] = w2v_; Tp[3] = w3v_;
}

// ---------------------------------------------------------------------------
// Kernel 2: EIGHT lanes per edge, ONE random 64 B line per edge.
// Lane sub owns out[4sub..4sub+3]:
//   needs nv[2sub..2sub+1]  -> own 4 B load  (bf16 pair)
//   needs attn quad:  sub<4 -> own exn quad (8 B load, same line)
//                     sub>=4 -> 4 ea-exps shuffled from lanes 2(sub-4),+1
// Each lane computes ea columns {2sub,2sub+1}: 16 fma + 66 score + 2 exp.
// Only 7 cross-lane ops (3 reduce + 4 redistribute) vs 15 in R8.
// ---------------------------------------------------------------------------
__global__ __launch_bounds__(256) void edge_attn8_kernel(
    const float* __restrict__ edge_attr, const int* __restrict__ col,
    const float* __restrict__ W_edge, const float* __restrict__ b_edge,
    const float* __restrict__ cst, const u32* __restrict__ T,
    float* __restrict__ out, int E)
{
    __shared__ float sWe[8 * OUT_C];   // [d][j] row-major, 512 B
    __shared__ float sbe[OUT_C];
    if (threadIdx.x < 32)
        ((f4*)sWe)[threadIdx.x] = ((const f4*)W_edge)[threadIdx.x];
    if (threadIdx.x < 4)
        ((f4*)sbe)[threadIdx.x] = ((const f4*)b_edge)[threadIdx.x];
    __syncthreads();

    const int tid = blockIdx.x * 256 + threadIdx.x;
    int e = tid >> 3;
    const bool valid = e < E;
    if (!valid) e = E - 1;
    const int lane = threadIdx.x & 63;
    const int sub  = lane & 7;
    const int base = lane & 56;

    // ---- memory: one random cached 64 B line + coalesced streams ------
    const int c = col[e];
    const char* Tb = (const char*)T + (size_t)c * 64;
    const u32 unv = *(const u32*)(Tb + 4 * sub);                 // nv pair
    const u64 uex = *(const u64*)(Tb + 32 + 8 * (sub & 3));      // exn quad

    const f4* ep = (const f4*)(edge_attr + (size_t)e * 8);
    f4 eaA = ep[0], eaB = ep[1];
    float ear[8] = {eaA[0], eaA[1], eaA[2], eaA[3],
                    eaB[0], eaB[1], eaB[2], eaB[3]};

    // ---- ea columns 2sub, 2sub+1 --------------------------------------
    f2 bp = ((const f2*)sbe)[sub];
    float eax = bp[0], eay = bp[1];
    #pragma unroll
    for (int d = 0; d < 8; d++) {
        f2 w = ((const f2*)sWe)[d * 8 + sub];
        eax = fmaf(ear[d], w[0], eax);
        eay = fmaf(ear[d], w[1], eay);
    }

    // ---- 2 scores -> exps (uniform consts: SGPR operands) -------------
    const float P = cst[0], Q = cst[1];
    float a0 = fmaf(P, eax, Q);
    float a1 = fmaf(P, eay, Q);
    #pragma unroll
    for (int j = 0; j < 16; j++) {
        const float r  = cst[2 + j];
        const float sp = cst[18 + j];
        a0 = fmaf(fabsf(eax + r), sp, a0);
        a1 = fmaf(fabsf(eay + r), sp, a1);
    }
    const float ex0 = __expf(a0);
    const float ex1 = __expf(a1);

    // ---- unpack bf16 --------------------------------------------------
    const float nvA = __uint_as_float(unv << 16);          // nv[2sub]
    const float nvB = __uint_as_float(unv & 0xffff0000u);  // nv[2sub+1]
    const u32 xlo = (u32)uex, xhi = (u32)(uex >> 32);
    const float x0 = __uint_as_float(xlo << 16);
    const float x1 = __uint_as_float(xlo & 0xffff0000u);
    const float x2 = __uint_as_float(xhi << 16);
    const float x3 = __uint_as_float(xhi & 0xffff0000u);

    // ---- denominator (exn quads live on lanes 0..3; avoid dup-count) --
    const float quad = (x0 + x1) + (x2 + x3);
    float ps = ex0 + ex1 + ((sub < 4) ? quad : 0.f);
    ps += __shfl_xor(ps, 1, 64);
    ps += __shfl_xor(ps, 2, 64);
    ps += __shfl_xor(ps, 4, 64);
    const float inv = __builtin_amdgcn_rcpf(ps);

    // ---- redistribute ea-exps to lanes 4..7 (4 shuffles) --------------
    const int sl = base | ((sub & 3) << 1);      // lane holding cols 4(sub-4),+1
    const float g0 = __shfl(ex0, sl,     64);
    const float g1 = __shfl(ex1, sl,     64);
    const float g2 = __shfl(ex0, sl | 1, 64);
    const float g3 = __shfl(ex1, sl | 1, 64);

    const bool lo4 = (sub < 4);
    const float m0 = lo4 ? x0 : g0, m1 = lo4 ? x1 : g1;
    const float m2 = lo4 ? x2 : g2, m3 = lo4 ? x3 : g3;

    // ---- out[e][4sub+q] = nv[(4sub+q)>>1] * attn -----------------------
    if (valid) {
        const float sA = nvA * inv, sB = nvB * inv;
        f4 o;
        o[0] = sA * m0; o[1] = sA * m1;
        o[2] = sB * m2; o[3] = sB * m3;
        ((f4*)(out + (size_t)e * 32))[sub] = o;  // plain store: 1 KB/wave, L2 merges
    }
}

// ---------------------------------------------------------------------------
extern "C" void kernel_launch(void* const* d_in, const int* in_sizes, int n_in,
                              void* d_out, int out_size, void* d_ws, size_t ws_size,
                              hipStream_t stream) {
    const float* x         = (const float*)d_in[0];
    const float* edge_attr = (const float*)d_in[1];
    const int*   col       = (const int*)d_in[2];
    const float* W_lin     = (const float*)d_in[3];
    const float* b_lin     = (const float*)d_in[4];
    const float* W_edge    = (const float*)d_in[5];
    const float* b_edge    = (const float*)d_in[6];
    const float* w1        = (const float*)d_in[7];
    const float* b1        = (const float*)d_in[8];
    const float* w2        = (const float*)d_in[9];
    const float* b2        = (const float*)d_in[10];
    float* out = (float*)d_out;

    const int N = in_sizes[0] / IN_C;     // 100000
    const int E = in_sizes[1] / 8;        // 1000000

    float* cst = (float*)d_ws;            // 64 floats (keeps T 256B-aligned)
    u32*   T   = (u32*)(cst + 64);        // N*16 u32 = 6.4 MB

    dim3 blk(256);
    dim3 grid1((N + 255) / 256);
    node_pack_kernel<<<grid1, blk, 0, stream>>>(x, W_lin, b_lin,
                                                w1, b1, w2, b2, cst, T, N);

    long long total = (long long)E * 8;   // 8 threads per edge
    dim3 grid2((unsigned)((total + 255) / 256));
    edge_attn8_kernel<<<grid2, blk, 0, stream>>>(edge_attr, col, W_edge, b_edge,
                                                 cst, T, out, E);
}